// Round 1
// baseline (117.482 us; speedup 1.0000x reference)
//
#include <hip/hip_runtime.h>
#include <math.h>

// Problem constants (from reference)
constexpr int ROWS = 32768;   // 2*16*1024
constexpr int COLS = 2048;
constexpr int K    = 512;
constexpr float EPS = 1e-5f;
constexpr int WPB  = 4;       // waves per block (1 row per wave)

// Each wave (64 lanes) owns one row:
//  1. stage the 2048-float row into LDS (coalesced float4)
//  2. gather 8 values/lane via col_indices
//  3. wave shfl reductions: mean/var -> normalize -> max -> exp/sum -> softmax
//  4. zero the LDS row, scatter softmax values, write out coalesced float4
__global__ __launch_bounds__(256) void fused_gather_ln_softmax_scatter(
    const float* __restrict__ x,
    const float* __restrict__ gamma,
    const float* __restrict__ beta,
    const int*   __restrict__ cidx,
    float*       __restrict__ out)
{
    __shared__ float lds[WPB][COLS];   // 32 KiB
    const int lane = threadIdx.x & 63;
    const int wv   = threadIdx.x >> 6;
    const int row  = blockIdx.x * WPB + wv;   // grid sized exactly ROWS/WPB

    // ---- stage row into LDS (2048 floats = 8 x float4 per lane) ----
    const float4* x4 = reinterpret_cast<const float4*>(x + (size_t)row * COLS);
    float4* l4 = reinterpret_cast<float4*>(lds[wv]);
    #pragma unroll
    for (int i = 0; i < 8; ++i)
        l4[i * 64 + lane] = x4[i * 64 + lane];

    // ---- load this lane's 8 column indices (coalesced int4 x2) ----
    const int4* i4 = reinterpret_cast<const int4*>(cidx + (size_t)row * K) + lane * 2;
    const int4 ia = i4[0], ib = i4[1];
    const int idx[8] = {ia.x, ia.y, ia.z, ia.w, ib.x, ib.y, ib.z, ib.w};

    __syncthreads();

    // ---- gather from LDS ----
    float v[8];
    #pragma unroll
    for (int j = 0; j < 8; ++j) v[j] = lds[wv][idx[j]];

    // ---- mean / biased variance over K=512 (wave reduction) ----
    float s = 0.f, ss = 0.f;
    #pragma unroll
    for (int j = 0; j < 8; ++j) { s += v[j]; ss += v[j] * v[j]; }
    #pragma unroll
    for (int off = 32; off >= 1; off >>= 1) {
        s  += __shfl_xor(s,  off, 64);
        ss += __shfl_xor(ss, off, 64);
    }
    const float mu   = s * (1.f / K);
    const float var  = ss * (1.f / K) - mu * mu;
    const float rstd = rsqrtf(var + EPS);

    // ---- gamma/beta for this lane's K-positions (k = lane*8 + j) ----
    const float4* g4 = reinterpret_cast<const float4*>(gamma) + lane * 2;
    const float4* b4 = reinterpret_cast<const float4*>(beta)  + lane * 2;
    const float4 ga = g4[0], gb = g4[1];
    const float4 ba = b4[0], bb = b4[1];
    const float g[8] = {ga.x, ga.y, ga.z, ga.w, gb.x, gb.y, gb.z, gb.w};
    const float b[8] = {ba.x, ba.y, ba.z, ba.w, bb.x, bb.y, bb.z, bb.w};

    // ---- normalize + row max ----
    float xn[8];
    float m = -INFINITY;
    #pragma unroll
    for (int j = 0; j < 8; ++j) {
        xn[j] = (v[j] - mu) * rstd * g[j] + b[j];
        m = fmaxf(m, xn[j]);
    }
    #pragma unroll
    for (int off = 32; off >= 1; off >>= 1)
        m = fmaxf(m, __shfl_xor(m, off, 64));

    // ---- exp + sum ----
    float p[8], ps = 0.f;
    #pragma unroll
    for (int j = 0; j < 8; ++j) { p[j] = __expf(xn[j] - m); ps += p[j]; }
    #pragma unroll
    for (int off = 32; off >= 1; off >>= 1)
        ps += __shfl_xor(ps, off, 64);
    const float inv = 1.f / ps;

    __syncthreads();   // all gathers done before the buffer is reused

    // ---- zero LDS row, scatter softmax values (DS ops are in-order per wave) ----
    const float4 z4 = make_float4(0.f, 0.f, 0.f, 0.f);
    #pragma unroll
    for (int i = 0; i < 8; ++i)
        l4[i * 64 + lane] = z4;
    #pragma unroll
    for (int j = 0; j < 8; ++j)
        lds[wv][idx[j]] = p[j] * inv;

    __syncthreads();

    // ---- coalesced store of the full row ----
    float4* o4 = reinterpret_cast<float4*>(out + (size_t)row * COLS);
    #pragma unroll
    for (int i = 0; i < 8; ++i)
        o4[i * 64 + lane] = l4[i * 64 + lane];
}

extern "C" void kernel_launch(void* const* d_in, const int* in_sizes, int n_in,
                              void* d_out, int out_size, void* d_ws, size_t ws_size,
                              hipStream_t stream) {
    const float* x     = (const float*)d_in[0];
    const float* gamma = (const float*)d_in[1];
    const float* beta  = (const float*)d_in[2];
    const int*   cidx  = (const int*)d_in[3];
    float* out = (float*)d_out;

    dim3 grid(ROWS / WPB);   // 8192 blocks
    dim3 block(256);
    hipLaunchKernelGGL(fused_gather_ln_softmax_scatter, grid, block, 0, stream,
                       x, gamma, beta, cidx, out);
}

// Round 3
// 102.914 us; speedup vs baseline: 1.1416x; 1.1416x over previous
//
#include <hip/hip_runtime.h>
#include <math.h>

// Problem constants (from reference)
constexpr int ROWS = 32768;   // 2*16*1024
constexpr int COLS = 2048;
constexpr int K    = 512;
constexpr float EPS = 1e-5f;
constexpr int WPB  = 4;       // waves per block (1 row per wave)

// clang ext_vector types — required by __builtin_nontemporal_load/store
// (HIP_vector_type structs are rejected).
typedef float f32x4 __attribute__((ext_vector_type(4)));
typedef int   i32x4 __attribute__((ext_vector_type(4)));

// Wave-level LDS fence: a wave64 executes in lockstep, so after draining this
// wave's own ds ops (lgkmcnt(0)) every lane's LDS writes are visible to every
// other lane of the SAME wave. No workgroup barrier needed (each wave owns its
// private LDS slice). sched_barrier(0) stops hipcc hoisting dependent ops past
// the inline-asm waitcnt (rule #18).
__device__ __forceinline__ void wave_lds_fence() {
    asm volatile("s_waitcnt lgkmcnt(0)" ::: "memory");
    __builtin_amdgcn_sched_barrier(0);
}

// Each wave (64 lanes) owns one row, fully independent of other waves:
//  1. stage the 2048-float row into LDS (coalesced nontemporal float4)
//  2. gather 8 values/lane via col_indices
//  3. wave shfl reductions: mean/var -> normalize -> max -> exp/sum -> softmax
//  4. zero the LDS row, scatter softmax values, write out coalesced NT float4
__global__ __launch_bounds__(256) void fused_gather_ln_softmax_scatter(
    const float* __restrict__ x,
    const float* __restrict__ gamma,
    const float* __restrict__ beta,
    const int*   __restrict__ cidx,
    float*       __restrict__ out)
{
    __shared__ float lds[WPB][COLS];   // 32 KiB
    const int lane = threadIdx.x & 63;
    const int wv   = threadIdx.x >> 6;
    const int row  = blockIdx.x * WPB + wv;   // grid sized exactly ROWS/WPB

    // ---- stage row into LDS (2048 floats = 8 x float4 per lane) ----
    const f32x4* x4 = reinterpret_cast<const f32x4*>(x + (size_t)row * COLS);
    f32x4* l4 = reinterpret_cast<f32x4*>(lds[wv]);
    #pragma unroll
    for (int i = 0; i < 8; ++i)
        l4[i * 64 + lane] = __builtin_nontemporal_load(&x4[i * 64 + lane]);

    // ---- load this lane's 8 column indices (coalesced int4 x2) ----
    const i32x4* i4 = reinterpret_cast<const i32x4*>(cidx + (size_t)row * K) + lane * 2;
    const i32x4 ia = __builtin_nontemporal_load(&i4[0]);
    const i32x4 ib = __builtin_nontemporal_load(&i4[1]);
    const int idx[8] = {ia.x, ia.y, ia.z, ia.w, ib.x, ib.y, ib.z, ib.w};

    // ---- gamma/beta for this lane's K-positions (k = lane*8 + j) ----
    const f32x4* g4 = reinterpret_cast<const f32x4*>(gamma) + lane * 2;
    const f32x4* b4 = reinterpret_cast<const f32x4*>(beta)  + lane * 2;
    const f32x4 ga = g4[0], gb = g4[1];
    const f32x4 ba = b4[0], bb = b4[1];
    const float g[8] = {ga.x, ga.y, ga.z, ga.w, gb.x, gb.y, gb.z, gb.w};
    const float b[8] = {ba.x, ba.y, ba.z, ba.w, bb.x, bb.y, bb.z, bb.w};

    wave_lds_fence();   // staging writes visible wave-wide

    // ---- gather from LDS ----
    float v[8];
    #pragma unroll
    for (int j = 0; j < 8; ++j) v[j] = lds[wv][idx[j]];

    // ---- mean / biased variance over K=512 (wave reduction) ----
    float s = 0.f, ss = 0.f;
    #pragma unroll
    for (int j = 0; j < 8; ++j) { s += v[j]; ss += v[j] * v[j]; }
    #pragma unroll
    for (int off = 32; off >= 1; off >>= 1) {
        s  += __shfl_xor(s,  off, 64);
        ss += __shfl_xor(ss, off, 64);
    }
    const float mu   = s * (1.f / K);
    const float var  = ss * (1.f / K) - mu * mu;
    const float rstd = rsqrtf(var + EPS);

    // ---- normalize + row max ----
    float xn[8];
    float m = -INFINITY;
    #pragma unroll
    for (int j = 0; j < 8; ++j) {
        xn[j] = (v[j] - mu) * rstd * g[j] + b[j];
        m = fmaxf(m, xn[j]);
    }
    #pragma unroll
    for (int off = 32; off >= 1; off >>= 1)
        m = fmaxf(m, __shfl_xor(m, off, 64));

    // ---- exp + sum ----
    float p[8], ps = 0.f;
    #pragma unroll
    for (int j = 0; j < 8; ++j) { p[j] = __expf(xn[j] - m); ps += p[j]; }
    #pragma unroll
    for (int off = 32; off >= 1; off >>= 1)
        ps += __shfl_xor(ps, off, 64);
    const float inv = 1.f / ps;

    // LDS ops from one wave execute in order: all gather reads above were
    // issued before the zero/scatter writes below, so no fence needed here
    // for the read-before-write hazard (compiler keeps may-alias ds order).

    // ---- zero LDS row, scatter softmax values ----
    const f32x4 z4 = (f32x4)(0.f);
    #pragma unroll
    for (int i = 0; i < 8; ++i)
        l4[i * 64 + lane] = z4;
    #pragma unroll
    for (int j = 0; j < 8; ++j)
        lds[wv][idx[j]] = p[j] * inv;

    wave_lds_fence();   // zero+scatter visible wave-wide before readback

    // ---- coalesced nontemporal store of the full row ----
    f32x4* o4 = reinterpret_cast<f32x4*>(out + (size_t)row * COLS);
    #pragma unroll
    for (int i = 0; i < 8; ++i)
        __builtin_nontemporal_store(l4[i * 64 + lane], &o4[i * 64 + lane]);
}

extern "C" void kernel_launch(void* const* d_in, const int* in_sizes, int n_in,
                              void* d_out, int out_size, void* d_ws, size_t ws_size,
                              hipStream_t stream) {
    const float* x     = (const float*)d_in[0];
    const float* gamma = (const float*)d_in[1];
    const float* beta  = (const float*)d_in[2];
    const int*   cidx  = (const int*)d_in[3];
    float* out = (float*)d_out;

    dim3 grid(ROWS / WPB);   // 8192 blocks
    dim3 block(256);
    hipLaunchKernelGGL(fused_gather_ln_softmax_scatter, grid, block, 0, stream,
                       x, gamma, beta, cidx, out);
}

// Round 4
// 92.904 us; speedup vs baseline: 1.2646x; 1.1077x over previous
//
#include <hip/hip_runtime.h>
#include <math.h>

// Problem constants (from reference)
constexpr int ROWS = 32768;   // 2*16*1024
constexpr int COLS = 2048;
constexpr int K    = 512;
constexpr float EPS = 1e-5f;
constexpr int WPB  = 4;       // waves per block (1 row per wave)

// clang ext_vector types — required by __builtin_nontemporal_load/store
typedef float f32x4 __attribute__((ext_vector_type(4)));
typedef int   i32x4 __attribute__((ext_vector_type(4)));

// Wave-level fences (wave64 lockstep; each wave owns a private LDS slice, so
// no workgroup barriers are needed anywhere). sched_barrier(0) after each
// inline-asm waitcnt stops hipcc hoisting dependent ops past it (rule #18).
__device__ __forceinline__ void wave_vm_fence() {
    asm volatile("s_waitcnt vmcnt(0)" ::: "memory");
    __builtin_amdgcn_sched_barrier(0);
}
__device__ __forceinline__ void wave_lds_fence() {
    asm volatile("s_waitcnt lgkmcnt(0)" ::: "memory");
    __builtin_amdgcn_sched_barrier(0);
}

// Each wave (64 lanes) owns one row, fully independent of other waves:
//  1. DMA the 2048-float row into LDS via global_load_lds (16B/lane, no VGPR
//     round-trip; dest = wave-uniform base + lane*16 — exactly our layout)
//  2. gather 8 values/lane via col_indices
//  3. wave shfl reductions: mean/var -> normalize -> max -> exp/sum -> softmax
//  4. zero the LDS row, scatter softmax values, write out coalesced NT float4
__global__ __launch_bounds__(256) void fused_gather_ln_softmax_scatter(
    const float* __restrict__ x,
    const float* __restrict__ gamma,
    const float* __restrict__ beta,
    const int*   __restrict__ cidx,
    float*       __restrict__ out)
{
    __shared__ float lds[WPB][COLS];   // 32 KiB
    const int lane = threadIdx.x & 63;
    const int wv   = threadIdx.x >> 6;
    const int row  = blockIdx.x * WPB + wv;   // grid sized exactly ROWS/WPB

    // ---- stage row into LDS: 8 x global_load_lds_dwordx4 per wave-lane ----
    const f32x4* x4 = reinterpret_cast<const f32x4*>(x + (size_t)row * COLS);
    #pragma unroll
    for (int i = 0; i < 8; ++i) {
        // global src is per-lane; LDS dest base is wave-uniform, HW adds lane*16
        __builtin_amdgcn_global_load_lds(
            reinterpret_cast<const unsigned int*>(&x4[i * 64 + lane]),
            reinterpret_cast<unsigned int*>(&lds[wv][i * 256]),
            16, 0, 0);
    }

    // ---- load this lane's 8 column indices (coalesced int4 x2, NT) ----
    const i32x4* i4 = reinterpret_cast<const i32x4*>(cidx + (size_t)row * K) + lane * 2;
    const i32x4 ia = __builtin_nontemporal_load(&i4[0]);
    const i32x4 ib = __builtin_nontemporal_load(&i4[1]);
    const int idx[8] = {ia.x, ia.y, ia.z, ia.w, ib.x, ib.y, ib.z, ib.w};

    // ---- gamma/beta for this lane's K-positions (k = lane*8 + j) ----
    const f32x4* g4 = reinterpret_cast<const f32x4*>(gamma) + lane * 2;
    const f32x4* b4 = reinterpret_cast<const f32x4*>(beta)  + lane * 2;
    const f32x4 ga = g4[0], gb = g4[1];
    const f32x4 ba = b4[0], bb = b4[1];
    const float g[8] = {ga.x, ga.y, ga.z, ga.w, gb.x, gb.y, gb.z, gb.w};
    const float b[8] = {ba.x, ba.y, ba.z, ba.w, bb.x, bb.y, bb.z, bb.w};

    wave_vm_fence();    // DMA staging (vmcnt) complete -> LDS row valid

    // ---- gather from LDS ----
    float v[8];
    #pragma unroll
    for (int j = 0; j < 8; ++j) v[j] = lds[wv][idx[j]];

    // ---- mean / biased variance over K=512 (wave reduction) ----
    float s = 0.f, ss = 0.f;
    #pragma unroll
    for (int j = 0; j < 8; ++j) { s += v[j]; ss += v[j] * v[j]; }
    #pragma unroll
    for (int off = 32; off >= 1; off >>= 1) {
        s  += __shfl_xor(s,  off, 64);
        ss += __shfl_xor(ss, off, 64);
    }
    const float mu   = s * (1.f / K);
    const float var  = ss * (1.f / K) - mu * mu;
    const float rstd = rsqrtf(var + EPS);

    // ---- normalize + row max ----
    float xn[8];
    float m = -INFINITY;
    #pragma unroll
    for (int j = 0; j < 8; ++j) {
        xn[j] = (v[j] - mu) * rstd * g[j] + b[j];
        m = fmaxf(m, xn[j]);
    }
    #pragma unroll
    for (int off = 32; off >= 1; off >>= 1)
        m = fmaxf(m, __shfl_xor(m, off, 64));

    // ---- exp + sum ----
    float p[8], ps = 0.f;
    #pragma unroll
    for (int j = 0; j < 8; ++j) { p[j] = __expf(xn[j] - m); ps += p[j]; }
    #pragma unroll
    for (int off = 32; off >= 1; off >>= 1)
        ps += __shfl_xor(ps, off, 64);
    const float inv = 1.f / ps;

    // Per-wave DS ops execute in order: gather reads were issued before the
    // zero/scatter writes below (compiler preserves may-alias ds order).

    // ---- zero LDS row, scatter softmax values ----
    f32x4* l4 = reinterpret_cast<f32x4*>(lds[wv]);
    const f32x4 z4 = (f32x4)(0.f);
    #pragma unroll
    for (int i = 0; i < 8; ++i)
        l4[i * 64 + lane] = z4;
    #pragma unroll
    for (int j = 0; j < 8; ++j)
        lds[wv][idx[j]] = p[j] * inv;

    wave_lds_fence();   // zero+scatter visible wave-wide before readback

    // ---- coalesced nontemporal store of the full row ----
    f32x4* o4 = reinterpret_cast<f32x4*>(out + (size_t)row * COLS);
    #pragma unroll
    for (int i = 0; i < 8; ++i)
        __builtin_nontemporal_store(l4[i * 64 + lane], &o4[i * 64 + lane]);
}

extern "C" void kernel_launch(void* const* d_in, const int* in_sizes, int n_in,
                              void* d_out, int out_size, void* d_ws, size_t ws_size,
                              hipStream_t stream) {
    const float* x     = (const float*)d_in[0];
    const float* gamma = (const float*)d_in[1];
    const float* beta  = (const float*)d_in[2];
    const int*   cidx  = (const int*)d_in[3];
    float* out = (float*)d_out;

    dim3 grid(ROWS / WPB);   // 8192 blocks
    dim3 block(256);
    hipLaunchKernelGGL(fused_gather_ln_softmax_scatter, grid, block, 0, stream,
                       x, gamma, beta, cidx, out);
}